// Round 3
// baseline (503.756 us; speedup 1.0000x reference)
//
#include <hip/hip_runtime.h>
#include <hip/hip_cooperative_groups.h>

namespace cg = cooperative_groups;

// Segment-normalized chunked linear, FUSED single cooperative kernel:
//   phase 1: stream x, per-segment sum of |x@W.T| row-sums -> LDS hist -> global atomics
//   grid.sync()
//   phase 2: re-stream x (L3-hot: phase 1 just pulled it), normalize, NT-store out
// 1024 blocks @ 4 blocks/CU = exactly co-resident on 256 CUs; each block owns
// 2 chunks of 4096 rows. LDS = 4097+4096 ints/floats = 32.8 KB -> 4 blocks/CU fits 160 KB.

#define NSEG  4096
#define BLK   256
#define RPT   16                  // rows per thread per chunk
#define BATCH 8                   // loads in flight back-to-back
#define CHUNK (BLK * RPT)         // 4096 rows
#define NB    1024                // co-resident grid (4/CU x 256 CU)

typedef float v4 __attribute__((ext_vector_type(4)));

__device__ __forceinline__ float absrow(v4 v, const float* w) {
    float y0 = fabsf(v.x * w[0]  + v.y * w[1]  + v.z * w[2]  + v.w * w[3]);
    float y1 = fabsf(v.x * w[4]  + v.y * w[5]  + v.z * w[6]  + v.w * w[7]);
    float y2 = fabsf(v.x * w[8]  + v.y * w[9]  + v.z * w[10] + v.w * w[11]);
    float y3 = fabsf(v.x * w[12] + v.y * w[13] + v.z * w[14] + v.w * w[15]);
    return (y0 + y1) + (y2 + y3);
}

__global__ __launch_bounds__(BLK, 4) void seg_fused(
    const v4* __restrict__ x, const int* __restrict__ slices,
    const float* __restrict__ W, float* __restrict__ seg_abs,
    v4* __restrict__ out, int n, int nchunks)
{
    __shared__ int   sl[NSEG + 1];
    __shared__ float hist[NSEG];
#pragma unroll
    for (int i = threadIdx.x; i < NSEG + 1; i += BLK) sl[i] = slices[i];
#pragma unroll
    for (int i = threadIdx.x; i < NSEG; i += BLK) hist[i] = 0.0f;

    float w[16];
#pragma unroll
    for (int i = 0; i < 16; ++i) w[i] = W[i];
    __syncthreads();

    // ---------------- phase 1: accumulate |y| per segment ----------------
    for (int c = blockIdx.x; c < nchunks; c += NB) {
        const int base = c * CHUNK + threadIdx.x;

        int lo = 0, hi = NSEG;
        {
            int r0 = (base < n) ? base : (n - 1);
            while (hi - lo > 1) { int mid = (lo + hi) >> 1; if (sl[mid] <= r0) lo = mid; else hi = mid; }
        }
        int seg = lo;
        float acc = 0.0f;

        const bool full = (base + (RPT - 1) * BLK) < n;
        if (full) {
#pragma unroll
            for (int b = 0; b < RPT / BATCH; ++b) {
                v4 d[BATCH];
#pragma unroll
                for (int j = 0; j < BATCH; ++j)
                    d[j] = x[base + (b * BATCH + j) * BLK];
#pragma unroll
                for (int j = 0; j < BATCH; ++j) {
                    int r = base + (b * BATCH + j) * BLK;
                    int s = seg;
                    while (s < NSEG - 1 && sl[s + 1] <= r) ++s;
                    if (s != seg) { atomicAdd(&hist[seg], acc); acc = 0.0f; seg = s; }
                    acc += absrow(d[j], w);
                }
            }
        } else {
            for (int it = 0; it < RPT; ++it) {
                int r = base + it * BLK;
                if (r < n) {
                    int s = seg;
                    while (s < NSEG - 1 && sl[s + 1] <= r) ++s;
                    if (s != seg) { atomicAdd(&hist[seg], acc); acc = 0.0f; seg = s; }
                    acc += absrow(x[r], w);
                }
            }
        }
        if (acc != 0.0f) atomicAdd(&hist[seg], acc);
    }
    __syncthreads();

    // flush block-local histogram (few nonzero bins per block)
#pragma unroll
    for (int i = threadIdx.x; i < NSEG; i += BLK) {
        float h = hist[i];
        if (h != 0.0f) atomicAdd(&seg_abs[i], h);
    }

    __threadfence();            // make atomics visible device-wide
    cg::this_grid().sync();     // all segment sums complete

    // ---------------- phase 2: normalize + NT store ----------------
    for (int c = blockIdx.x; c < nchunks; c += NB) {
        const int base = c * CHUNK + threadIdx.x;

        int lo = 0, hi = NSEG;
        {
            int r0 = (base < n) ? base : (n - 1);
            while (hi - lo > 1) { int mid = (lo + hi) >> 1; if (sl[mid] <= r0) lo = mid; else hi = mid; }
        }
        int seg = lo;
        // agent-scope atomic load: bypasses any stale L1/L2 across XCDs
        float inv = 1.0f / __hip_atomic_load(&seg_abs[seg], __ATOMIC_RELAXED, __HIP_MEMORY_SCOPE_AGENT);

        const bool full = (base + (RPT - 1) * BLK) < n;
        if (full) {
#pragma unroll
            for (int b = 0; b < RPT / BATCH; ++b) {
                v4 d[BATCH];
#pragma unroll
                for (int j = 0; j < BATCH; ++j)
                    d[j] = x[base + (b * BATCH + j) * BLK];
#pragma unroll
                for (int j = 0; j < BATCH; ++j) {
                    int r = base + (b * BATCH + j) * BLK;
                    int s = seg;
                    while (s < NSEG - 1 && sl[s + 1] <= r) ++s;
                    if (s != seg) {
                        seg = s;
                        inv = 1.0f / __hip_atomic_load(&seg_abs[seg], __ATOMIC_RELAXED, __HIP_MEMORY_SCOPE_AGENT);
                    }
                    v4 v = d[j], o;
                    o.x = (v.x * w[0]  + v.y * w[1]  + v.z * w[2]  + v.w * w[3])  * inv;
                    o.y = (v.x * w[4]  + v.y * w[5]  + v.z * w[6]  + v.w * w[7])  * inv;
                    o.z = (v.x * w[8]  + v.y * w[9]  + v.z * w[10] + v.w * w[11]) * inv;
                    o.w = (v.x * w[12] + v.y * w[13] + v.z * w[14] + v.w * w[15]) * inv;
                    __builtin_nontemporal_store(o, &out[r]);   // don't evict x from L3
                }
            }
        } else {
            for (int it = 0; it < RPT; ++it) {
                int r = base + it * BLK;
                if (r < n) {
                    int s = seg;
                    while (s < NSEG - 1 && sl[s + 1] <= r) ++s;
                    if (s != seg) {
                        seg = s;
                        inv = 1.0f / __hip_atomic_load(&seg_abs[seg], __ATOMIC_RELAXED, __HIP_MEMORY_SCOPE_AGENT);
                    }
                    v4 v = x[r], o;
                    o.x = (v.x * w[0]  + v.y * w[1]  + v.z * w[2]  + v.w * w[3])  * inv;
                    o.y = (v.x * w[4]  + v.y * w[5]  + v.z * w[6]  + v.w * w[7])  * inv;
                    o.z = (v.x * w[8]  + v.y * w[9]  + v.z * w[10] + v.w * w[11]) * inv;
                    o.w = (v.x * w[12] + v.y * w[13] + v.z * w[14] + v.w * w[15]) * inv;
                    __builtin_nontemporal_store(o, &out[r]);
                }
            }
        }
    }
}

extern "C" void kernel_launch(void* const* d_in, const int* in_sizes, int n_in,
                              void* d_out, int out_size, void* d_ws, size_t ws_size,
                              hipStream_t stream) {
    const v4*    x       = (const v4*)d_in[0];
    const int*   slices  = (const int*)d_in[1];
    const float* W       = (const float*)d_in[2];
    float*       seg_abs = (float*)d_ws;      // NSEG floats of scratch
    v4*          out     = (v4*)d_out;
    int n = in_sizes[0] / 4;                  // number of rows
    int nchunks = (n + CHUNK - 1) / CHUNK;    // 2048

    hipMemsetAsync(d_ws, 0, NSEG * sizeof(float), stream);  // ws is poisoned 0xAA

    void* args[] = {(void*)&x, (void*)&slices, (void*)&W, (void*)&seg_abs,
                    (void*)&out, (void*)&n, (void*)&nchunks};
    hipLaunchCooperativeKernel((void*)seg_fused, dim3(NB), dim3(BLK), args, 0, stream);
}